// Round 10
// baseline (1014.921 us; speedup 1.0000x reference)
//
#include <hip/hip_runtime.h>
#include <hip/hip_bf16.h>
#include <float.h>
#include <stdint.h>

typedef __attribute__((ext_vector_type(8))) short bf16x8;
typedef __attribute__((ext_vector_type(4))) float f32x4;

#define NCH 320      // A*K = 5*64 output channels of GEMM1
#define NCG 20       // 320 / 16 channel-groups
#define GEMM_GRID 2048
#define HTS 332      // LDS h-tile row stride (shorts): rg banks {0,24,16,8}

static __device__ __forceinline__ unsigned short f2bf(float f) {
    union { float f; unsigned int u; } v; v.f = f;
    unsigned int u = v.u;
    u += 0x7FFFu + ((u >> 16) & 1u);   // RNE
    return (unsigned short)(u >> 16);
}

static __device__ __forceinline__ float bf2f(unsigned short h) {
    union { unsigned int u; float f; } v; v.u = ((unsigned int)h) << 16;
    return v.f;
}

// ---- K0a: seg_start[b] = lower_bound(batch, b) ------------------------------
__global__ void seg_start_kernel(const int* __restrict__ batch,
                                 int* __restrict__ seg, int n, int b_gr) {
    int b = blockIdx.x * blockDim.x + threadIdx.x;
    if (b > b_gr) return;
    int lo = 0, hi = n;
    while (lo < hi) {
        int mid = (lo + hi) >> 1;
        if (batch[mid] < b) lo = mid + 1; else hi = mid;
    }
    seg[b] = lo;
}

// ---- K0b: pack W1 into bf16 B-fragment layout -------------------------------
// frag (cg, ks): lane l, elem j <- W1[k = ks*32 + (l>>4)*8 + j][c = cg*16 + (l&15)]
__global__ void pack_w1_kernel(const float* __restrict__ W1,
                               unsigned short* __restrict__ w1p) {
    int idx = blockIdx.x * blockDim.x + threadIdx.x;
    if (idx >= NCG * 8 * 64) return;
    int lane = idx & 63;
    int ks = (idx >> 6) & 7;
    int cg = idx >> 9;
    int col = cg * 16 + (lane & 15);
    int kbase = ks * 32 + (lane >> 4) * 8;
    unsigned short* dst = w1p + (size_t)idx * 8;
#pragma unroll
    for (int j = 0; j < 8; ++j)
        dst[j] = f2bf(W1[(size_t)(kbase + j) * NCH + col]);
}

// ---- K1: DENSE GEMM  h[npad][320] (bf16, row-major) = x @ W1 ----------------
// 512 thr / 8 waves. Wave w: cg-group q = w>>1 (cgs 5q..5q+4), tile-pair
// tp = w&1 (16-row tiles 2tp, 2tp+1). B fragments streamed from L2 (w1p is
// 160 KB, L2-resident, shared by all blocks) -> low VGPR -> 2 blocks/CU.
// LDS: xs 32 KB (single buffer) + ht 42.5 KB = 75 KB. TLP hides latency.
__global__ __launch_bounds__(512)
__attribute__((amdgpu_waves_per_eu(4)))
void gemm_h_kernel(const float* __restrict__ x,
                   const unsigned short* __restrict__ w1p,
                   unsigned short* __restrict__ h,
                   int n, int nchunks, int span) {
    __shared__ unsigned short xs[64 * 256];   // 32 KB, XOR-swizzled bf16
    __shared__ unsigned short ht[64 * HTS];   // 42.5 KB h-tile

    const int tid = threadIdx.x;
    const int lane = tid & 63;
    const int w = tid >> 6;          // 0..7
    const int q = w >> 1;            // cg-group: cgs 5q..5q+4
    const int tp = w & 1;            // tile-pair: tiles 2tp, 2tp+1
    const int rg = lane >> 4;
    const int col = lane & 15;
    const int tileoff = tp * 16384;  // 2tp * 8192 bytes

    // swizzled LDS read offsets (within a tile; +8192 for second tile)
    int addrk[8];
#pragma unroll
    for (int ks = 0; ks < 8; ++ks)
        addrk[ks] = ((col * 512) + (rg * 16) + ks * 64) ^ ((col & 7) << 4);

    const bf16x8* wp = (const bf16x8*)w1p;
    const float4* xv = (const float4*)x;

    const int c0 = blockIdx.x * span;
    const int c1 = min(c0 + span, nchunks);
    if (c0 >= c1) return;

#define COOPST(TC) { \
        unsigned short* hb_ = h + (size_t)((TC) << 6) * NCH; \
        _Pragma("unroll") \
        for (int i_ = 0; i_ < 10; ++i_) { \
            int q_ = tid + i_ * 512; \
            int row_ = q_ / 80; int cid_ = q_ - row_ * 80; \
            uint2 v_ = *(const uint2*)(ht + row_ * HTS + cid_ * 4); \
            *(uint2*)(hb_ + row_ * NCH + cid_ * 4) = v_; } }

    for (int tc = c0; tc < c1; ++tc) {
        const int base = tc << 6;
        const int rem = min(n - base, 64);
        // ---- stage loads (issued first; latency overlaps coop-store) ----
        float4 p[8];
#pragma unroll
        for (int i = 0; i < 8; ++i) {
            int qq = tid + i * 512; int row = qq >> 6;
            p[i] = make_float4(0.f, 0.f, 0.f, 0.f);
            if (row < rem) p[i] = xv[(size_t)(base + row) * 64 + (qq & 63)];
        }
        // ---- coop-store previous chunk's ht -> h (fire-and-forget) ----
        if (tc > c0) COOPST(tc - 1)
        // ---- convert + write xs ----
#pragma unroll
        for (int i = 0; i < 8; ++i) {
            int qq = tid + i * 512; int row = qq >> 6;
            int byt = ((row * 512) + ((qq & 63) * 8)) ^ ((row & 7) << 4);
            __hip_bfloat162 lo2 = __float22bfloat162_rn(make_float2(p[i].x, p[i].y));
            __hip_bfloat162 hi2 = __float22bfloat162_rn(make_float2(p[i].z, p[i].w));
            unsigned int ulo, uhi;
            __builtin_memcpy(&ulo, &lo2, 4); __builtin_memcpy(&uhi, &hi2, 4);
            *(uint2*)((char*)xs + byt) = make_uint2(ulo, uhi);
        }
        __syncthreads();   // xs ready; all ht readers done
        // ---- compute: B streamed from L2 each ks ----
        f32x4 c00 = {0,0,0,0}, c01 = {0,0,0,0}, c02 = {0,0,0,0},
              c03 = {0,0,0,0}, c04 = {0,0,0,0};
        f32x4 c10 = {0,0,0,0}, c11 = {0,0,0,0}, c12 = {0,0,0,0},
              c13 = {0,0,0,0}, c14 = {0,0,0,0};
#pragma unroll
        for (int ks = 0; ks < 8; ++ks) {
            const char* pb = (const char*)xs + tileoff;
            bf16x8 a0 = *(const bf16x8*)(pb + addrk[ks]);
            bf16x8 a1 = *(const bf16x8*)(pb + addrk[ks] + 8192);
            bf16x8 b0 = wp[((5 * q + 0) * 8 + ks) * 64 + lane];
            bf16x8 b1 = wp[((5 * q + 1) * 8 + ks) * 64 + lane];
            bf16x8 b2 = wp[((5 * q + 2) * 8 + ks) * 64 + lane];
            bf16x8 b3 = wp[((5 * q + 3) * 8 + ks) * 64 + lane];
            bf16x8 b4 = wp[((5 * q + 4) * 8 + ks) * 64 + lane];
            c00 = __builtin_amdgcn_mfma_f32_16x16x32_bf16(a0, b0, c00, 0, 0, 0);
            c10 = __builtin_amdgcn_mfma_f32_16x16x32_bf16(a1, b0, c10, 0, 0, 0);
            c01 = __builtin_amdgcn_mfma_f32_16x16x32_bf16(a0, b1, c01, 0, 0, 0);
            c11 = __builtin_amdgcn_mfma_f32_16x16x32_bf16(a1, b1, c11, 0, 0, 0);
            c02 = __builtin_amdgcn_mfma_f32_16x16x32_bf16(a0, b2, c02, 0, 0, 0);
            c12 = __builtin_amdgcn_mfma_f32_16x16x32_bf16(a1, b2, c12, 0, 0, 0);
            c03 = __builtin_amdgcn_mfma_f32_16x16x32_bf16(a0, b3, c03, 0, 0, 0);
            c13 = __builtin_amdgcn_mfma_f32_16x16x32_bf16(a1, b3, c13, 0, 0, 0);
            c04 = __builtin_amdgcn_mfma_f32_16x16x32_bf16(a0, b4, c04, 0, 0, 0);
            c14 = __builtin_amdgcn_mfma_f32_16x16x32_bf16(a1, b4, c14, 0, 0, 0);
        }
        // ---- accs -> ht (bf16). D row = tile*16 + rg*4 + r, col lane&15 ----
        {
            const int tr0 = tp * 32 + rg * 4;     // tile 2tp
            const int tr1 = tr0 + 16;             // tile 2tp+1
#define STLDS(ACC, J, TR) { int a_ = (TR) * HTS + (5 * q + (J)) * 16 + col; \
            ht[a_] = f2bf((ACC)[0]); \
            ht[a_ + HTS] = f2bf((ACC)[1]); \
            ht[a_ + 2 * HTS] = f2bf((ACC)[2]); \
            ht[a_ + 3 * HTS] = f2bf((ACC)[3]); }
            STLDS(c00, 0, tr0) STLDS(c10, 0, tr1)
            STLDS(c01, 1, tr0) STLDS(c11, 1, tr1)
            STLDS(c02, 2, tr0) STLDS(c12, 2, tr1)
            STLDS(c03, 3, tr0) STLDS(c13, 3, tr1)
            STLDS(c04, 4, tr0) STLDS(c14, 4, tr1)
#undef STLDS
        }
        __syncthreads();   // ht complete; xs consumed
    }
    COOPST(c1 - 1)
#undef COOPST
}

// ---- K2: segment reduce over row-major h -> z[B][320] -----------------------
// Block = one graph, 320 thr. Thread t: channels {2u, 2u+1} (u = t mod 160),
// rows of parity t/160. One uint load per row -> fully coalesced.
__global__ __launch_bounds__(320) void reduce_kernel(
    const unsigned short* __restrict__ h, const int* __restrict__ seg,
    float* __restrict__ z) {
    __shared__ float red[160][8];
    const int g = blockIdx.x;
    const int sgr = seg[g], en = seg[g + 1];
    const int cnt = en - sgr;
    const int t = threadIdx.x;
    const int half = (t >= 160) ? 1 : 0;
    const int u = t - half * 160;

    float s0 = 0.f, q0 = 0.f, mn0 = FLT_MAX, mx0 = -FLT_MAX;
    float s1 = 0.f, q1 = 0.f, mn1 = FLT_MAX, mx1 = -FLT_MAX;
    const unsigned short* bp = h + 2 * u;
    for (int r = sgr + half; r < en; r += 2) {
        unsigned int uu = *(const unsigned int*)(bp + (size_t)r * NCH);
        float v0 = bf2f((unsigned short)(uu & 0xFFFFu));
        float v1 = bf2f((unsigned short)(uu >> 16));
        s0 += v0; q0 += v0 * v0; mn0 = fminf(mn0, v0); mx0 = fmaxf(mx0, v0);
        s1 += v1; q1 += v1 * v1; mn1 = fminf(mn1, v1); mx1 = fmaxf(mx1, v1);
    }
    if (half) {
        red[u][0] = s0; red[u][1] = q0; red[u][2] = mn0; red[u][3] = mx0;
        red[u][4] = s1; red[u][5] = q1; red[u][6] = mn1; red[u][7] = mx1;
    }
    __syncthreads();
    if (!half) {
        s0 += red[u][0]; q0 += red[u][1];
        mn0 = fminf(mn0, red[u][2]); mx0 = fmaxf(mx0, red[u][3]);
        s1 += red[u][4]; q1 += red[u][5];
        mn1 = fminf(mn1, red[u][6]); mx1 = fmaxf(mx1, red[u][7]);
        const float cntf = (float)max(cnt, 1);
        const int a = u >> 5;          // aggregator id, same for both channels
        float r0, r1;
        if (a == 0) { r0 = s0; r1 = s1; }
        else if (a == 1) { r0 = mn0; r1 = mn1; }
        else if (a == 2) { r0 = mx0; r1 = mx1; }
        else if (a == 3) { r0 = s0 / cntf; r1 = s1 / cntf; }
        else {
            float m0 = s0 / cntf, m1 = s1 / cntf;
            r0 = sqrtf(fmaxf(q0 / cntf - m0 * m0, 1e-5f));
            r1 = sqrtf(fmaxf(q1 / cntf - m1 * m1, 1e-5f));
        }
        *(float2*)(z + (size_t)g * NCH + 2 * u) = make_float2(r0, r1);
    }
}

// ---- K3: out = z @ W2 + b ---------------------------------------------------
__global__ __launch_bounds__(256) void k2_kernel(
    const float* __restrict__ z, const float* __restrict__ W2,
    const float* __restrict__ bias, float* __restrict__ out) {
    __shared__ float zf[NCH][17];   // +1 pad -> conflict-free transpose
    const int g0 = blockIdx.x * 16;
    const int tid = threadIdx.x;
    for (int idx = tid; idx < 16 * NCH; idx += 256) {
        int m = idx / NCH;          // graph within tile
        int c = idx - m * NCH;      // channel (fastest -> coalesced z reads)
        zf[c][m] = z[(size_t)(g0 + m) * NCH + c];
    }
    __syncthreads();
    float acc[16];
#pragma unroll
    for (int m = 0; m < 16; ++m) acc[m] = 0.f;
    for (int k = 0; k < NCH; ++k) {
        float wv = W2[(size_t)k * 256 + tid];
#pragma unroll
        for (int m = 0; m < 16; ++m) acc[m] += zf[k][m] * wv;
    }
    float bv = bias[tid];
#pragma unroll
    for (int m = 0; m < 16; ++m)
        out[(size_t)(g0 + m) * 256 + tid] = acc[m] + bv;
}

extern "C" void kernel_launch(void* const* d_in, const int* in_sizes, int n_in,
                              void* d_out, int out_size, void* d_ws, size_t ws_size,
                              hipStream_t stream) {
    const float* x = (const float*)d_in[0];
    const int* batch = (const int*)d_in[1];
    const float* W1 = (const float*)d_in[3];
    const float* W2 = (const float*)d_in[4];
    const float* bias = (const float*)d_in[5];

    const int n = in_sizes[1];           // 500000 nodes
    const int b_gr = out_size / 256;     // 8192 graphs
    const int nchunks = (n + 63) >> 6;   // 7813
    const int span = (nchunks + GEMM_GRID - 1) / GEMM_GRID;

    char* ws = (char*)d_ws;
    unsigned short* w1p = (unsigned short*)ws;               // 160 KB
    int* seg = (int*)(ws + 163840);                          // (B+1)*4
    float* z = (float*)(ws + 262144);                        // B*320*4 = 10.5 MB
    unsigned short* h = (unsigned short*)(ws + 262144 +
                         (size_t)b_gr * NCH * sizeof(float)); // npad*320*2 = 320 MB

    seg_start_kernel<<<(b_gr + 256) / 256, 256, 0, stream>>>(batch, seg, n, b_gr);
    pack_w1_kernel<<<(NCG * 8 * 64 + 255) / 256, 256, 0, stream>>>(W1, w1p);
    gemm_h_kernel<<<GEMM_GRID, 512, 0, stream>>>(x, w1p, h, n, nchunks, span);
    reduce_kernel<<<b_gr, 320, 0, stream>>>(h, seg, z);
    k2_kernel<<<b_gr / 16, 256, 0, stream>>>(z, W2, bias, (float*)d_out);
}

// Round 11
// 466.857 us; speedup vs baseline: 2.1739x; 2.1739x over previous
//
#include <hip/hip_runtime.h>
#include <hip/hip_bf16.h>
#include <float.h>
#include <stdint.h>

typedef __attribute__((ext_vector_type(8))) short bf16x8;
typedef __attribute__((ext_vector_type(4))) float f32x4;

#define NCH 320      // A*K = 5*64 output channels of GEMM1
#define NCG 20       // 320 / 16 channel-groups
#define GEMM_GRID 1024
#define HTS 332      // LDS h-tile row stride (shorts): rg banks {0,24,16,8}

static __device__ __forceinline__ unsigned short f2bf(float f) {
    union { float f; unsigned int u; } v; v.f = f;
    unsigned int u = v.u;
    u += 0x7FFFu + ((u >> 16) & 1u);   // RNE
    return (unsigned short)(u >> 16);
}

static __device__ __forceinline__ float bf2f(unsigned short h) {
    union { unsigned int u; float f; } v; v.u = ((unsigned int)h) << 16;
    return v.f;
}

// ---- K0a: seg_start[b] = lower_bound(batch, b) ------------------------------
__global__ void seg_start_kernel(const int* __restrict__ batch,
                                 int* __restrict__ seg, int n, int b_gr) {
    int b = blockIdx.x * blockDim.x + threadIdx.x;
    if (b > b_gr) return;
    int lo = 0, hi = n;
    while (lo < hi) {
        int mid = (lo + hi) >> 1;
        if (batch[mid] < b) lo = mid + 1; else hi = mid;
    }
    seg[b] = lo;
}

// ---- K0b: pack W1 into bf16 B-fragment layout -------------------------------
// frag (cg, ks): lane l, elem j <- W1[k = ks*32 + (l>>4)*8 + j][c = cg*16 + (l&15)]
__global__ void pack_w1_kernel(const float* __restrict__ W1,
                               unsigned short* __restrict__ w1p) {
    int idx = blockIdx.x * blockDim.x + threadIdx.x;
    if (idx >= NCG * 8 * 64) return;
    int lane = idx & 63;
    int ks = (idx >> 6) & 7;
    int cg = idx >> 9;
    int col = cg * 16 + (lane & 15);
    int kbase = ks * 32 + (lane >> 4) * 8;
    unsigned short* dst = w1p + (size_t)idx * 8;
#pragma unroll
    for (int j = 0; j < 8; ++j)
        dst[j] = f2bf(W1[(size_t)(kbase + j) * NCH + col]);
}

// ---- K1: DENSE GEMM  h[npad][320] (bf16, row-major) = x @ W1 ----------------
// r9 structure (pins, waves_per_eu(2), wave w: cgs {w,w+8} + std cg 16+(w&3)
// on row-half p==w>>2) with ONE change: single xs buffer -> LDS 74.5 KB ->
// 2 blocks/CU (16 waves/CU). Cross-block TLP hides the serial chain.
__global__ __launch_bounds__(512)
__attribute__((amdgpu_waves_per_eu(2)))
void gemm_h_kernel(const float* __restrict__ x,
                   const unsigned short* __restrict__ w1p,
                   unsigned short* __restrict__ h,
                   int n, int nchunks, int span) {
    __shared__ unsigned short xs[64 * 256];   // 32 KB, XOR-swizzled bf16
    __shared__ unsigned short ht[64 * HTS];   // 42.5 KB h-tile

    const int tid = threadIdx.x;
    const int lane = tid & 63;
    const int w = tid >> 6;          // 0..7
    const int rg = lane >> 4;
    const int col = lane & 15;
    const int chA = w * 16 + col;               // cgs 0..7
    const int chB = (w + 8) * 16 + col;         // cgs 8..15
    const int chS = (16 + (w & 3)) * 16 + col;  // cgs 16..19
    const int sthalf = w >> 2;                  // std pass for this wave

    // persistent B fragments (3 cgs x 8 ks = 96 VGPR), pinned vs remat
    const bf16x8* wp = (const bf16x8*)w1p;
    bf16x8 B0[8], B1[8], Bs[8];
#pragma unroll
    for (int ks = 0; ks < 8; ++ks) {
        B0[ks] = wp[(w * 8 + ks) * 64 + lane];
        B1[ks] = wp[((w + 8) * 8 + ks) * 64 + lane];
        Bs[ks] = wp[((16 + (w & 3)) * 8 + ks) * 64 + lane];
        asm volatile("" : "+v"(B0[ks]));
        asm volatile("" : "+v"(B1[ks]));
        asm volatile("" : "+v"(Bs[ks]));
    }

    // swizzled LDS read offsets (tile 0; tile+1 adds 8192, pass adds 16384)
    int addrk[8];
#pragma unroll
    for (int ks = 0; ks < 8; ++ks)
        addrk[ks] = ((col * 512) + (rg * 16) + ks * 64) ^ ((col & 7) << 4);

    const float4* xv = (const float4*)x;
    const int c0 = blockIdx.x * span;
    const int c1 = min(c0 + span, nchunks);
    if (c0 >= c1) return;

#define COOPST(TC) { \
        unsigned short* hb_ = h + (size_t)((TC) << 6) * NCH; \
        _Pragma("unroll") \
        for (int i_ = 0; i_ < 10; ++i_) { \
            int q_ = tid + i_ * 512; \
            int row_ = q_ / 80; int cid_ = q_ - row_ * 80; \
            uint2 v_ = *(const uint2*)(ht + row_ * HTS + cid_ * 4); \
            *(uint2*)(hb_ + row_ * NCH + cid_ * 4) = v_; } }

    for (int tc = c0; tc < c1; ++tc) {
        const int base = tc << 6;
        const int rem = min(n - base, 64);
        // ---- issue current chunk's loads (latency overlaps coop-store) ----
        float4 p[8];
#pragma unroll
        for (int i = 0; i < 8; ++i) {
            int qq = tid + i * 512; int row = qq >> 6;
            p[i] = make_float4(0.f, 0.f, 0.f, 0.f);
            if (row < rem) p[i] = xv[(size_t)(base + row) * 64 + (qq & 63)];
        }
        // ---- coop-store previous chunk's ht -> h ----
        if (tc > c0) COOPST(tc - 1)
        // ---- convert + write xs ----
#pragma unroll
        for (int i = 0; i < 8; ++i) {
            int qq = tid + i * 512; int row = qq >> 6;
            int byt = ((row * 512) + ((qq & 63) * 8)) ^ ((row & 7) << 4);
            __hip_bfloat162 lo2 = __float22bfloat162_rn(make_float2(p[i].x, p[i].y));
            __hip_bfloat162 hi2 = __float22bfloat162_rn(make_float2(p[i].z, p[i].w));
            unsigned int ulo, uhi;
            __builtin_memcpy(&ulo, &lo2, 4); __builtin_memcpy(&uhi, &hi2, 4);
            *(uint2*)((char*)xs + byt) = make_uint2(ulo, uhi);
        }
        __syncthreads();   // xs ready; all ht readers done
        // ---- compute: 2 half-passes x 8 ks ----
#pragma unroll
        for (int ps = 0; ps < 2; ++ps) {
            f32x4 aA0 = {0,0,0,0}, aA1 = {0,0,0,0};
            f32x4 aB0 = {0,0,0,0}, aB1 = {0,0,0,0};
            f32x4 aS0 = {0,0,0,0}, aS1 = {0,0,0,0};
            const char* pb = (const char*)xs + ps * 16384;
            const bool dostd = (sthalf == ps);   // wave-uniform
#pragma unroll
            for (int ks = 0; ks < 8; ++ks) {
                bf16x8 x0 = *(const bf16x8*)(pb + addrk[ks]);
                bf16x8 x1 = *(const bf16x8*)(pb + addrk[ks] + 8192);
                aA0 = __builtin_amdgcn_mfma_f32_16x16x32_bf16(x0, B0[ks], aA0, 0, 0, 0);
                aB0 = __builtin_amdgcn_mfma_f32_16x16x32_bf16(x0, B1[ks], aB0, 0, 0, 0);
                aA1 = __builtin_amdgcn_mfma_f32_16x16x32_bf16(x1, B0[ks], aA1, 0, 0, 0);
                aB1 = __builtin_amdgcn_mfma_f32_16x16x32_bf16(x1, B1[ks], aB1, 0, 0, 0);
                if (dostd) {
                    aS0 = __builtin_amdgcn_mfma_f32_16x16x32_bf16(x0, Bs[ks], aS0, 0, 0, 0);
                    aS1 = __builtin_amdgcn_mfma_f32_16x16x32_bf16(x1, Bs[ks], aS1, 0, 0, 0);
                }
            }
            // D layout: tile-row = ps*32 + tile16*16 + rg*4 + r, col lane&15
            const int tr0 = ps * 32 + rg * 4;     // tile 2ps
            const int tr1 = tr0 + 16;             // tile 2ps+1
#define STLDS(ACC, CH, TR) { int a_ = (TR) * HTS + (CH); \
            ht[a_] = f2bf((ACC)[0]); \
            ht[a_ + HTS] = f2bf((ACC)[1]); \
            ht[a_ + 2 * HTS] = f2bf((ACC)[2]); \
            ht[a_ + 3 * HTS] = f2bf((ACC)[3]); }
            STLDS(aA0, chA, tr0)
            STLDS(aA1, chA, tr1)
            STLDS(aB0, chB, tr0)
            STLDS(aB1, chB, tr1)
            if (dostd) {
                STLDS(aS0, chS, tr0)
                STLDS(aS1, chS, tr1)
            }
#undef STLDS
        }
        __syncthreads();   // ht complete; xs consumed
    }
    COOPST(c1 - 1)
#undef COOPST
}

// ---- K2: segment reduce over row-major h -> z[B][320] -----------------------
// Block = one graph, 320 thr. Thread t: channels {2u, 2u+1} (u = t mod 160),
// rows of parity t/160. One uint load per row -> fully coalesced.
__global__ __launch_bounds__(320) void reduce_kernel(
    const unsigned short* __restrict__ h, const int* __restrict__ seg,
    float* __restrict__ z) {
    __shared__ float red[160][8];
    const int g = blockIdx.x;
    const int sgr = seg[g], en = seg[g + 1];
    const int cnt = en - sgr;
    const int t = threadIdx.x;
    const int half = (t >= 160) ? 1 : 0;
    const int u = t - half * 160;

    float s0 = 0.f, q0 = 0.f, mn0 = FLT_MAX, mx0 = -FLT_MAX;
    float s1 = 0.f, q1 = 0.f, mn1 = FLT_MAX, mx1 = -FLT_MAX;
    const unsigned short* bp = h + 2 * u;
    for (int r = sgr + half; r < en; r += 2) {
        unsigned int uu = *(const unsigned int*)(bp + (size_t)r * NCH);
        float v0 = bf2f((unsigned short)(uu & 0xFFFFu));
        float v1 = bf2f((unsigned short)(uu >> 16));
        s0 += v0; q0 += v0 * v0; mn0 = fminf(mn0, v0); mx0 = fmaxf(mx0, v0);
        s1 += v1; q1 += v1 * v1; mn1 = fminf(mn1, v1); mx1 = fmaxf(mx1, v1);
    }
    if (half) {
        red[u][0] = s0; red[u][1] = q0; red[u][2] = mn0; red[u][3] = mx0;
        red[u][4] = s1; red[u][5] = q1; red[u][6] = mn1; red[u][7] = mx1;
    }
    __syncthreads();
    if (!half) {
        s0 += red[u][0]; q0 += red[u][1];
        mn0 = fminf(mn0, red[u][2]); mx0 = fmaxf(mx0, red[u][3]);
        s1 += red[u][4]; q1 += red[u][5];
        mn1 = fminf(mn1, red[u][6]); mx1 = fmaxf(mx1, red[u][7]);
        const float cntf = (float)max(cnt, 1);
        const int a = u >> 5;          // aggregator id, same for both channels
        float r0, r1;
        if (a == 0) { r0 = s0; r1 = s1; }
        else if (a == 1) { r0 = mn0; r1 = mn1; }
        else if (a == 2) { r0 = mx0; r1 = mx1; }
        else if (a == 3) { r0 = s0 / cntf; r1 = s1 / cntf; }
        else {
            float m0 = s0 / cntf, m1 = s1 / cntf;
            r0 = sqrtf(fmaxf(q0 / cntf - m0 * m0, 1e-5f));
            r1 = sqrtf(fmaxf(q1 / cntf - m1 * m1, 1e-5f));
        }
        *(float2*)(z + (size_t)g * NCH + 2 * u) = make_float2(r0, r1);
    }
}

// ---- K3: out = z @ W2 + b ---------------------------------------------------
__global__ __launch_bounds__(256) void k2_kernel(
    const float* __restrict__ z, const float* __restrict__ W2,
    const float* __restrict__ bias, float* __restrict__ out) {
    __shared__ float zf[NCH][17];   // +1 pad -> conflict-free transpose
    const int g0 = blockIdx.x * 16;
    const int tid = threadIdx.x;
    for (int idx = tid; idx < 16 * NCH; idx += 256) {
        int m = idx / NCH;          // graph within tile
        int c = idx - m * NCH;      // channel (fastest -> coalesced z reads)
        zf[c][m] = z[(size_t)(g0 + m) * NCH + c];
    }
    __syncthreads();
    float acc[16];
#pragma unroll
    for (int m = 0; m < 16; ++m) acc[m] = 0.f;
    for (int k = 0; k < NCH; ++k) {
        float wv = W2[(size_t)k * 256 + tid];
#pragma unroll
        for (int m = 0; m < 16; ++m) acc[m] += zf[k][m] * wv;
    }
    float bv = bias[tid];
#pragma unroll
    for (int m = 0; m < 16; ++m)
        out[(size_t)(g0 + m) * 256 + tid] = acc[m] + bv;
}

extern "C" void kernel_launch(void* const* d_in, const int* in_sizes, int n_in,
                              void* d_out, int out_size, void* d_ws, size_t ws_size,
                              hipStream_t stream) {
    const float* x = (const float*)d_in[0];
    const int* batch = (const int*)d_in[1];
    const float* W1 = (const float*)d_in[3];
    const float* W2 = (const float*)d_in[4];
    const float* bias = (const float*)d_in[5];

    const int n = in_sizes[1];           // 500000 nodes
    const int b_gr = out_size / 256;     // 8192 graphs
    const int nchunks = (n + 63) >> 6;   // 7813
    const int span = (nchunks + GEMM_GRID - 1) / GEMM_GRID;

    char* ws = (char*)d_ws;
    unsigned short* w1p = (unsigned short*)ws;               // 160 KB
    int* seg = (int*)(ws + 163840);                          // (B+1)*4
    float* z = (float*)(ws + 262144);                        // B*320*4 = 10.5 MB
    unsigned short* h = (unsigned short*)(ws + 262144 +
                         (size_t)b_gr * NCH * sizeof(float)); // npad*320*2 = 320 MB

    seg_start_kernel<<<(b_gr + 256) / 256, 256, 0, stream>>>(batch, seg, n, b_gr);
    pack_w1_kernel<<<(NCG * 8 * 64 + 255) / 256, 256, 0, stream>>>(W1, w1p);
    gemm_h_kernel<<<GEMM_GRID, 512, 0, stream>>>(x, w1p, h, n, nchunks, span);
    reduce_kernel<<<b_gr, 320, 0, stream>>>(h, seg, z);
    k2_kernel<<<b_gr / 16, 256, 0, stream>>>(z, W2, bias, (float*)d_out);
}

// Round 12
// 398.587 us; speedup vs baseline: 2.5463x; 1.1713x over previous
//
#include <hip/hip_runtime.h>
#include <hip/hip_bf16.h>
#include <float.h>
#include <stdint.h>

typedef __attribute__((ext_vector_type(8))) short bf16x8;
typedef __attribute__((ext_vector_type(4))) float f32x4;

#define NCH 320      // A*K = 5*64 output channels of GEMM1
#define NCG 20       // 320 / 16 channel-groups
#define GEMM_GRID 1024

static __device__ __forceinline__ unsigned short f2bf(float f) {
    union { float f; unsigned int u; } v; v.f = f;
    unsigned int u = v.u;
    u += 0x7FFFu + ((u >> 16) & 1u);   // RNE
    return (unsigned short)(u >> 16);
}

static __device__ __forceinline__ float bf2f(unsigned short h) {
    union { unsigned int u; float f; } v; v.u = ((unsigned int)h) << 16;
    return v.f;
}

// ---- K0a: seg_start[b] = lower_bound(batch, b) ------------------------------
__global__ void seg_start_kernel(const int* __restrict__ batch,
                                 int* __restrict__ seg, int n, int b_gr) {
    int b = blockIdx.x * blockDim.x + threadIdx.x;
    if (b > b_gr) return;
    int lo = 0, hi = n;
    while (lo < hi) {
        int mid = (lo + hi) >> 1;
        if (batch[mid] < b) lo = mid + 1; else hi = mid;
    }
    seg[b] = lo;
}

// ---- K0b: pack W1 into bf16 B-fragment layout -------------------------------
// frag (cg, ks): lane l, elem j <- W1[k = ks*32 + (l>>4)*8 + j][c = cg*16 + (l&15)]
__global__ void pack_w1_kernel(const float* __restrict__ W1,
                               unsigned short* __restrict__ w1p) {
    int idx = blockIdx.x * blockDim.x + threadIdx.x;
    if (idx >= NCG * 8 * 64) return;
    int lane = idx & 63;
    int ks = (idx >> 6) & 7;
    int cg = idx >> 9;
    int col = cg * 16 + (lane & 15);
    int kbase = ks * 32 + (lane >> 4) * 8;
    unsigned short* dst = w1p + (size_t)idx * 8;
#pragma unroll
    for (int j = 0; j < 8; ++j)
        dst[j] = f2bf(W1[(size_t)(kbase + j) * NCH + col]);
}

// ---- K1: DENSE GEMM  h[npad/4][320][4] (bf16) = x @ W1 ----------------------
// 512 thr / 8 waves. Wave w: cgs {w, w+8} all rows + std cg 16+(w&3) on the
// row-half ps == w>>2. h stored DIRECTLY (each acc's 4 rows contiguous ->
// coalesced 8 B stores) -- no LDS transpose tile, no coop-store phase.
// waves_per_eu(2,2): 256-reg budget so pinned B (96) + in-flight p[8] (32)
// + accs coexist -> staged loads genuinely span the compute phase (the only
// vmcnt(0) drain is the post-compute __syncthreads).
__global__ __launch_bounds__(512)
__attribute__((amdgpu_waves_per_eu(2, 2)))
void gemm_h_kernel(const float* __restrict__ x,
                   const unsigned short* __restrict__ w1p,
                   unsigned short* __restrict__ h,
                   int n, int nchunks, int span) {
    __shared__ unsigned short xs[64 * 256];   // 32 KB, XOR-swizzled bf16

    const int tid = threadIdx.x;
    const int lane = tid & 63;
    const int w = tid >> 6;          // 0..7
    const int rg = lane >> 4;
    const int col = lane & 15;
    const int chA = w * 16 + col;               // cgs 0..7
    const int chB = (w + 8) * 16 + col;         // cgs 8..15
    const int chS = (16 + (w & 3)) * 16 + col;  // cgs 16..19
    const int sthalf = w >> 2;                  // std pass for this wave

    // persistent B fragments (3 cgs x 8 ks = 96 VGPR), pinned vs remat
    const bf16x8* wp = (const bf16x8*)w1p;
    bf16x8 B0[8], B1[8], Bs[8];
#pragma unroll
    for (int ks = 0; ks < 8; ++ks) {
        B0[ks] = wp[(w * 8 + ks) * 64 + lane];
        B1[ks] = wp[((w + 8) * 8 + ks) * 64 + lane];
        Bs[ks] = wp[((16 + (w & 3)) * 8 + ks) * 64 + lane];
        asm volatile("" : "+v"(B0[ks]));
        asm volatile("" : "+v"(B1[ks]));
        asm volatile("" : "+v"(Bs[ks]));
    }

    // swizzled LDS read offsets (tile 0; tile+1 adds 8192, pass adds 16384)
    int addrk[8];
#pragma unroll
    for (int ks = 0; ks < 8; ++ks)
        addrk[ks] = ((col * 512) + (rg * 16) + ks * 64) ^ ((col & 7) << 4);

    const float4* xv = (const float4*)x;
    const int c0 = blockIdx.x * span;
    const int c1 = min(c0 + span, nchunks);
    if (c0 >= c1) return;

#define LD8(CH) { const int base_ = (CH) << 6; \
        const int rem_ = min(n - base_, 64); \
        _Pragma("unroll") \
        for (int i_ = 0; i_ < 8; ++i_) { \
            int q_ = tid + i_ * 512; int row_ = q_ >> 6; \
            p[i_] = make_float4(0.f, 0.f, 0.f, 0.f); \
            if (row_ < rem_) p[i_] = xv[(size_t)(base_ + row_) * 64 + (q_ & 63)]; } }

#define ST8() { \
        _Pragma("unroll") \
        for (int i_ = 0; i_ < 8; ++i_) { \
            int q_ = tid + i_ * 512; int row_ = q_ >> 6; \
            int byt_ = ((row_ * 512) + ((q_ & 63) * 8)) ^ ((row_ & 7) << 4); \
            __hip_bfloat162 lo2_ = __float22bfloat162_rn(make_float2(p[i_].x, p[i_].y)); \
            __hip_bfloat162 hi2_ = __float22bfloat162_rn(make_float2(p[i_].z, p[i_].w)); \
            unsigned int ulo_, uhi_; \
            __builtin_memcpy(&ulo_, &lo2_, 4); __builtin_memcpy(&uhi_, &hi2_, 4); \
            *(uint2*)((char*)xs + byt_) = make_uint2(ulo_, uhi_); } }

    // ---- prologue: stage chunk c0 ----
    {
        float4 p[8];
        LD8(c0)
        ST8()
    }
    __syncthreads();

    for (int tc = c0; tc < c1; ++tc) {
        const bool more = (tc + 1 < c1);
        float4 p[8];
        if (more) LD8(tc + 1)        // issue early; in flight through compute
        // ---- compute chunk tc from xs; direct coalesced h stores ----
        const int base = tc << 6;
#pragma unroll
        for (int ps = 0; ps < 2; ++ps) {
            f32x4 aA0 = {0,0,0,0}, aA1 = {0,0,0,0};
            f32x4 aB0 = {0,0,0,0}, aB1 = {0,0,0,0};
            f32x4 aS0 = {0,0,0,0}, aS1 = {0,0,0,0};
            const char* pb = (const char*)xs + ps * 16384;
            const bool dostd = (sthalf == ps);   // wave-uniform
#pragma unroll
            for (int ks = 0; ks < 8; ++ks) {
                bf16x8 x0 = *(const bf16x8*)(pb + addrk[ks]);
                bf16x8 x1 = *(const bf16x8*)(pb + addrk[ks] + 8192);
                aA0 = __builtin_amdgcn_mfma_f32_16x16x32_bf16(x0, B0[ks], aA0, 0, 0, 0);
                aB0 = __builtin_amdgcn_mfma_f32_16x16x32_bf16(x0, B1[ks], aB0, 0, 0, 0);
                aA1 = __builtin_amdgcn_mfma_f32_16x16x32_bf16(x1, B0[ks], aA1, 0, 0, 0);
                aB1 = __builtin_amdgcn_mfma_f32_16x16x32_bf16(x1, B1[ks], aB1, 0, 0, 0);
                if (dostd) {
                    aS0 = __builtin_amdgcn_mfma_f32_16x16x32_bf16(x0, Bs[ks], aS0, 0, 0, 0);
                    aS1 = __builtin_amdgcn_mfma_f32_16x16x32_bf16(x1, Bs[ks], aS1, 0, 0, 0);
                }
            }
            // D: row = base + ps*32 + tile16*16 + rg*4 + r (4 rows = one nb4)
            const int rb0 = base + ps * 32 + rg * 4;   // tile 2ps
            const int rb1 = rb0 + 16;                  // tile 2ps+1
            unsigned short* hp0 = h + (size_t)(rb0 >> 2) * 1280;
            unsigned short* hp1 = h + (size_t)(rb1 >> 2) * 1280;
#define STG(ACC, CH, HP) { \
            __hip_bfloat162 lo2 = __float22bfloat162_rn(make_float2((ACC)[0], (ACC)[1])); \
            __hip_bfloat162 hi2 = __float22bfloat162_rn(make_float2((ACC)[2], (ACC)[3])); \
            uint2 pk2; \
            __builtin_memcpy(&pk2.x, &lo2, 4); __builtin_memcpy(&pk2.y, &hi2, 4); \
            *(uint2*)((HP) + (CH) * 4) = pk2; }
            STG(aA0, chA, hp0)
            STG(aA1, chA, hp1)
            STG(aB0, chB, hp0)
            STG(aB1, chB, hp1)
            if (dostd) {
                STG(aS0, chS, hp0)
                STG(aS1, chS, hp1)
            }
#undef STG
        }
        __syncthreads();   // xs consumed by all waves; drains loads (+stores)
        if (more) {
            ST8()
            __syncthreads();   // xs ready for next iteration
        }
    }
#undef LD8
#undef ST8
}

// ---- K2: segment reduce over h[nb4][320][4] -> z[B][320] --------------------
// Block = one graph, 320 thr, thread t = channel t. One uint2 per 4 rows;
// 320 consecutive threads read 2560 B contiguous -> fully coalesced. Boundary
// rows masked branchlessly. No cross-thread combine needed (zero LDS).
__global__ __launch_bounds__(320) void reduce_kernel(
    const unsigned short* __restrict__ h, const int* __restrict__ seg,
    float* __restrict__ z) {
    const int g = blockIdx.x;
    const int sg = seg[g], en = seg[g + 1];
    const int cnt = en - sg;
    const int t = threadIdx.x;

    float s = 0.f, q = 0.f, mn = FLT_MAX, mx = -FLT_MAX;
    if (cnt > 0) {
        const unsigned short* hp = h + (size_t)t * 4;
        const int b40 = sg >> 2, b41 = (en - 1) >> 2;
        for (int b4 = b40; b4 <= b41; ++b4) {
            uint2 u = *(const uint2*)(hp + (size_t)b4 * 1280);
            const int r0 = b4 << 2;
#pragma unroll
            for (int j = 0; j < 4; ++j) {
                unsigned short e = (j < 2)
                    ? (unsigned short)((j == 0) ? (u.x & 0xFFFFu) : (u.x >> 16))
                    : (unsigned short)((j == 2) ? (u.y & 0xFFFFu) : (u.y >> 16));
                float v = bf2f(e);
                bool inr = (r0 + j >= sg) && (r0 + j < en);
                s += inr ? v : 0.f;
                q += inr ? v * v : 0.f;
                mn = fminf(mn, inr ? v : FLT_MAX);
                mx = fmaxf(mx, inr ? v : -FLT_MAX);
            }
        }
    }
    const float cntf = (float)max(cnt, 1);
    const int a = t >> 6;
    float res;
    if (a == 0) res = s;
    else if (a == 1) res = mn;
    else if (a == 2) res = mx;
    else if (a == 3) res = s / cntf;
    else {
        float m1 = s / cntf, m2 = q / cntf;
        res = sqrtf(fmaxf(m2 - m1 * m1, 1e-5f));
    }
    z[(size_t)g * NCH + t] = res;
}

// ---- K3: out = z @ W2 + b ---------------------------------------------------
__global__ __launch_bounds__(256) void k2_kernel(
    const float* __restrict__ z, const float* __restrict__ W2,
    const float* __restrict__ bias, float* __restrict__ out) {
    __shared__ float zf[NCH][17];   // +1 pad -> conflict-free transpose
    const int g0 = blockIdx.x * 16;
    const int tid = threadIdx.x;
    for (int idx = tid; idx < 16 * NCH; idx += 256) {
        int m = idx / NCH;          // graph within tile
        int c = idx - m * NCH;      // channel (fastest -> coalesced z reads)
        zf[c][m] = z[(size_t)(g0 + m) * NCH + c];
    }
    __syncthreads();
    float acc[16];
#pragma unroll
    for (int m = 0; m < 16; ++m) acc[m] = 0.f;
    for (int k = 0; k < NCH; ++k) {
        float wv = W2[(size_t)k * 256 + tid];
#pragma unroll
        for (int m = 0; m < 16; ++m) acc[m] += zf[k][m] * wv;
    }
    float bv = bias[tid];
#pragma unroll
    for (int m = 0; m < 16; ++m)
        out[(size_t)(g0 + m) * 256 + tid] = acc[m] + bv;
}

extern "C" void kernel_launch(void* const* d_in, const int* in_sizes, int n_in,
                              void* d_out, int out_size, void* d_ws, size_t ws_size,
                              hipStream_t stream) {
    const float* x = (const float*)d_in[0];
    const int* batch = (const int*)d_in[1];
    const float* W1 = (const float*)d_in[3];
    const float* W2 = (const float*)d_in[4];
    const float* bias = (const float*)d_in[5];

    const int n = in_sizes[1];           // 500000 nodes
    const int b_gr = out_size / 256;     // 8192 graphs
    const int nchunks = (n + 63) >> 6;   // 7813
    const int span = (nchunks + GEMM_GRID - 1) / GEMM_GRID;

    char* ws = (char*)d_ws;
    unsigned short* w1p = (unsigned short*)ws;               // 160 KB
    int* seg = (int*)(ws + 163840);                          // (B+1)*4
    float* z = (float*)(ws + 262144);                        // B*320*4 = 10.5 MB
    unsigned short* h = (unsigned short*)(ws + 262144 +
                         (size_t)b_gr * NCH * sizeof(float)); // npad*320*2 = 320 MB

    seg_start_kernel<<<(b_gr + 256) / 256, 256, 0, stream>>>(batch, seg, n, b_gr);
    pack_w1_kernel<<<(NCG * 8 * 64 + 255) / 256, 256, 0, stream>>>(W1, w1p);
    gemm_h_kernel<<<GEMM_GRID, 512, 0, stream>>>(x, w1p, h, n, nchunks, span);
    reduce_kernel<<<b_gr, 320, 0, stream>>>(h, seg, z);
    k2_kernel<<<b_gr / 16, 256, 0, stream>>>(z, W2, bias, (float*)d_out);
}

// Round 13
// 350.143 us; speedup vs baseline: 2.8986x; 1.1384x over previous
//
#include <hip/hip_runtime.h>
#include <hip/hip_bf16.h>
#include <float.h>
#include <stdint.h>

typedef __attribute__((ext_vector_type(8))) short bf16x8;
typedef __attribute__((ext_vector_type(4))) float f32x4;

#define NCH 320      // A*K = 5*64 output channels of GEMM1
#define NCG 20       // 320 / 16 channel-groups
#define GEMM_GRID 512

static __device__ __forceinline__ unsigned short f2bf(float f) {
    union { float f; unsigned int u; } v; v.f = f;
    unsigned int u = v.u;
    u += 0x7FFFu + ((u >> 16) & 1u);   // RNE
    return (unsigned short)(u >> 16);
}

static __device__ __forceinline__ float bf2f(unsigned short h) {
    union { unsigned int u; float f; } v; v.u = ((unsigned int)h) << 16;
    return v.f;
}

// ---- K0a: seg_start[b] = lower_bound(batch, b) ------------------------------
__global__ void seg_start_kernel(const int* __restrict__ batch,
                                 int* __restrict__ seg, int n, int b_gr) {
    int b = blockIdx.x * blockDim.x + threadIdx.x;
    if (b > b_gr) return;
    int lo = 0, hi = n;
    while (lo < hi) {
        int mid = (lo + hi) >> 1;
        if (batch[mid] < b) lo = mid + 1; else hi = mid;
    }
    seg[b] = lo;
}

// ---- K0b: pack W1 into bf16 B-fragment layout -------------------------------
// frag (cg, ks): lane l, elem j <- W1[k = ks*32 + (l>>4)*8 + j][c = cg*16 + (l&15)]
__global__ void pack_w1_kernel(const float* __restrict__ W1,
                               unsigned short* __restrict__ w1p) {
    int idx = blockIdx.x * blockDim.x + threadIdx.x;
    if (idx >= NCG * 8 * 64) return;
    int lane = idx & 63;
    int ks = (idx >> 6) & 7;
    int cg = idx >> 9;
    int col = cg * 16 + (lane & 15);
    int kbase = ks * 32 + (lane >> 4) * 8;
    unsigned short* dst = w1p + (size_t)idx * 8;
#pragma unroll
    for (int j = 0; j < 8; ++j)
        dst[j] = f2bf(W1[(size_t)(kbase + j) * NCH + col]);
}

// ---- K1: DENSE GEMM  h[npad/4][320][4] (bf16) = x @ W1 ----------------------
// 512 thr / 8 waves; wave w: cgs {w, w+8} + std cg 16+(w&3) on row-half w>>2.
// KEY CHANGE vs r12: raw s_barrier with lgkmcnt(0)-ONLY waits (no vmcnt(0)
// drain -> prefetch loads and h-stores stay in flight across barriers), plus
// a 2-deep register pipeline (pA/pB) with double-buffered xs: loads for chunk
// t+2 issue at the top of phase t and are consumed one full phase later.
__global__ __launch_bounds__(512)
__attribute__((amdgpu_waves_per_eu(2, 2)))
void gemm_h_kernel(const float* __restrict__ x,
                   const unsigned short* __restrict__ w1p,
                   unsigned short* __restrict__ h,
                   int n, int nchunks, int span) {
    __shared__ unsigned short xs[2][64 * 256];   // 2 x 32 KB, XOR-swizzled bf16

    const int tid = threadIdx.x;
    const int lane = tid & 63;
    const int w = tid >> 6;          // 0..7
    const int rg = lane >> 4;
    const int col = lane & 15;
    const int chA = w * 16 + col;               // cgs 0..7
    const int chB = (w + 8) * 16 + col;         // cgs 8..15
    const int chS = (16 + (w & 3)) * 16 + col;  // cgs 16..19
    const int sthalf = w >> 2;                  // std pass for this wave

    // persistent B fragments (3 cgs x 8 ks = 96 VGPR), pinned vs remat
    const bf16x8* wp = (const bf16x8*)w1p;
    bf16x8 B0[8], B1[8], Bs[8];
#pragma unroll
    for (int ks = 0; ks < 8; ++ks) {
        B0[ks] = wp[(w * 8 + ks) * 64 + lane];
        B1[ks] = wp[((w + 8) * 8 + ks) * 64 + lane];
        Bs[ks] = wp[((16 + (w & 3)) * 8 + ks) * 64 + lane];
        asm volatile("" : "+v"(B0[ks]));
        asm volatile("" : "+v"(B1[ks]));
        asm volatile("" : "+v"(Bs[ks]));
    }

    // swizzled LDS read offsets (tile 0; tile+1 adds 8192, pass adds 16384)
    int addrk[8];
#pragma unroll
    for (int ks = 0; ks < 8; ++ks)
        addrk[ks] = ((col * 512) + (rg * 16) + ks * 64) ^ ((col & 7) << 4);

    const float4* xv = (const float4*)x;
    const int c0 = blockIdx.x * span;
    const int c1 = min(c0 + span, nchunks);
    if (c0 >= c1) return;

// raw barrier: order LDS only; leave vmem (loads AND stores) in flight
#define LGKBAR { asm volatile("s_waitcnt lgkmcnt(0)" ::: "memory"); \
                 __builtin_amdgcn_s_barrier(); \
                 asm volatile("" ::: "memory"); }

#define LDM(P, CH) { const int ch_ = (CH); const int base_ = ch_ << 6; \
        const int rem_ = (ch_ < c1) ? min(n - base_, 64) : 0; \
        _Pragma("unroll") \
        for (int i_ = 0; i_ < 8; ++i_) { \
            int q_ = tid + i_ * 512; int row_ = q_ >> 6; \
            P[i_] = make_float4(0.f, 0.f, 0.f, 0.f); \
            if (row_ < rem_) P[i_] = xv[(size_t)(base_ + row_) * 64 + (q_ & 63)]; } }

#define STM(P, BUF) { \
        _Pragma("unroll") \
        for (int i_ = 0; i_ < 8; ++i_) { \
            int q_ = tid + i_ * 512; int row_ = q_ >> 6; \
            int byt_ = ((row_ * 512) + ((q_ & 63) * 8)) ^ ((row_ & 7) << 4); \
            __hip_bfloat162 lo2_ = __float22bfloat162_rn(make_float2(P[i_].x, P[i_].y)); \
            __hip_bfloat162 hi2_ = __float22bfloat162_rn(make_float2(P[i_].z, P[i_].w)); \
            unsigned int ulo_, uhi_; \
            __builtin_memcpy(&ulo_, &lo2_, 4); __builtin_memcpy(&uhi_, &hi2_, 4); \
            *(uint2*)((char*)(xs[BUF]) + byt_) = make_uint2(ulo_, uhi_); } }

#define COMPUTE(TC, BUF) { \
        const int base = (TC) << 6; \
        _Pragma("unroll") \
        for (int ps = 0; ps < 2; ++ps) { \
            f32x4 aA0 = {0,0,0,0}, aA1 = {0,0,0,0}; \
            f32x4 aB0 = {0,0,0,0}, aB1 = {0,0,0,0}; \
            f32x4 aS0 = {0,0,0,0}, aS1 = {0,0,0,0}; \
            const char* pb = (const char*)(xs[BUF]) + ps * 16384; \
            const bool dostd = (sthalf == ps); \
            _Pragma("unroll") \
            for (int ks = 0; ks < 8; ++ks) { \
                bf16x8 x0 = *(const bf16x8*)(pb + addrk[ks]); \
                bf16x8 x1 = *(const bf16x8*)(pb + addrk[ks] + 8192); \
                aA0 = __builtin_amdgcn_mfma_f32_16x16x32_bf16(x0, B0[ks], aA0, 0, 0, 0); \
                aB0 = __builtin_amdgcn_mfma_f32_16x16x32_bf16(x0, B1[ks], aB0, 0, 0, 0); \
                aA1 = __builtin_amdgcn_mfma_f32_16x16x32_bf16(x1, B0[ks], aA1, 0, 0, 0); \
                aB1 = __builtin_amdgcn_mfma_f32_16x16x32_bf16(x1, B1[ks], aB1, 0, 0, 0); \
                if (dostd) { \
                    aS0 = __builtin_amdgcn_mfma_f32_16x16x32_bf16(x0, Bs[ks], aS0, 0, 0, 0); \
                    aS1 = __builtin_amdgcn_mfma_f32_16x16x32_bf16(x1, Bs[ks], aS1, 0, 0, 0); \
                } \
            } \
            const int rb0 = base + ps * 32 + rg * 4; \
            const int rb1 = rb0 + 16; \
            unsigned short* hp0 = h + (size_t)(rb0 >> 2) * 1280; \
            unsigned short* hp1 = h + (size_t)(rb1 >> 2) * 1280; \
            STG(aA0, chA, hp0) \
            STG(aA1, chA, hp1) \
            STG(aB0, chB, hp0) \
            STG(aB1, chB, hp1) \
            if (dostd) { \
                STG(aS0, chS, hp0) \
                STG(aS1, chS, hp1) \
            } \
        } }

#define STG(ACC, CH, HP) { \
        __hip_bfloat162 lo2 = __float22bfloat162_rn(make_float2((ACC)[0], (ACC)[1])); \
        __hip_bfloat162 hi2 = __float22bfloat162_rn(make_float2((ACC)[2], (ACC)[3])); \
        uint2 pk2; \
        __builtin_memcpy(&pk2.x, &lo2, 4); __builtin_memcpy(&pk2.y, &hi2, 4); \
        *(uint2*)((HP) + (CH) * 4) = pk2; }

    // ---- pipeline prologue: pA=c0, pB=c0+1 in flight; stage c0 ----
    float4 pA[8], pB[8];
    LDM(pA, c0)
    LDM(pB, c0 + 1)
    STM(pA, 0)           // compiler waits vmcnt for pA regs only
    LGKBAR

    int tc = c0;
    while (true) {
        // --- phase A: xs[0] = chunk tc; pB = chunk tc+1 (in flight) ---
        if (tc + 2 < c1) LDM(pA, tc + 2)
        COMPUTE(tc, 0)
        LGKBAR           // xs[0] consumed by all waves
        if (tc + 1 < c1) STM(pB, 1)
        LGKBAR           // xs[1] visible
        ++tc; if (tc >= c1) break;

        // --- phase B: xs[1] = chunk tc; pA = chunk tc+1 (in flight) ---
        if (tc + 2 < c1) LDM(pB, tc + 2)
        COMPUTE(tc, 1)
        LGKBAR           // xs[1] consumed
        if (tc + 1 < c1) STM(pA, 0)
        LGKBAR           // xs[0] visible
        ++tc; if (tc >= c1) break;
    }
#undef LGKBAR
#undef LDM
#undef STM
#undef COMPUTE
#undef STG
}

// ---- K2: segment reduce over h[nb4][320][4] -> z[B][320] --------------------
// Block = one graph, 320 thr, thread t = channel t. One uint2 per 4 rows;
// 320 consecutive threads read 2560 B contiguous -> fully coalesced.
__global__ __launch_bounds__(320) void reduce_kernel(
    const unsigned short* __restrict__ h, const int* __restrict__ seg,
    float* __restrict__ z) {
    const int g = blockIdx.x;
    const int sg = seg[g], en = seg[g + 1];
    const int cnt = en - sg;
    const int t = threadIdx.x;

    float s = 0.f, q = 0.f, mn = FLT_MAX, mx = -FLT_MAX;
    if (cnt > 0) {
        const unsigned short* hp = h + (size_t)t * 4;
        const int b40 = sg >> 2, b41 = (en - 1) >> 2;
        for (int b4 = b40; b4 <= b41; ++b4) {
            uint2 u = *(const uint2*)(hp + (size_t)b4 * 1280);
            const int r0 = b4 << 2;
#pragma unroll
            for (int j = 0; j < 4; ++j) {
                unsigned short e = (j < 2)
                    ? (unsigned short)((j == 0) ? (u.x & 0xFFFFu) : (u.x >> 16))
                    : (unsigned short)((j == 2) ? (u.y & 0xFFFFu) : (u.y >> 16));
                float v = bf2f(e);
                bool inr = (r0 + j >= sg) && (r0 + j < en);
                s += inr ? v : 0.f;
                q += inr ? v * v : 0.f;
                mn = fminf(mn, inr ? v : FLT_MAX);
                mx = fmaxf(mx, inr ? v : -FLT_MAX);
            }
        }
    }
    const float cntf = (float)max(cnt, 1);
    const int a = t >> 6;
    float res;
    if (a == 0) res = s;
    else if (a == 1) res = mn;
    else if (a == 2) res = mx;
    else if (a == 3) res = s / cntf;
    else {
        float m1 = s / cntf, m2 = q / cntf;
        res = sqrtf(fmaxf(m2 - m1 * m1, 1e-5f));
    }
    z[(size_t)g * NCH + t] = res;
}

// ---- K3: out = z @ W2 + b ---------------------------------------------------
__global__ __launch_bounds__(256) void k2_kernel(
    const float* __restrict__ z, const float* __restrict__ W2,
    const float* __restrict__ bias, float* __restrict__ out) {
    __shared__ float zf[NCH][17];   // +1 pad -> conflict-free transpose
    const int g0 = blockIdx.x * 16;
    const int tid = threadIdx.x;
    for (int idx = tid; idx < 16 * NCH; idx += 256) {
        int m = idx / NCH;          // graph within tile
        int c = idx - m * NCH;      // channel (fastest -> coalesced z reads)
        zf[c][m] = z[(size_t)(g0 + m) * NCH + c];
    }
    __syncthreads();
    float acc[16];
#pragma unroll
    for (int m = 0; m < 16; ++m) acc[m] = 0.f;
    for (int k = 0; k < NCH; ++k) {
        float wv = W2[(size_t)k * 256 + tid];
#pragma unroll
        for (int m = 0; m < 16; ++m) acc[m] += zf[k][m] * wv;
    }
    float bv = bias[tid];
#pragma unroll
    for (int m = 0; m < 16; ++m)
        out[(size_t)(g0 + m) * 256 + tid] = acc[m] + bv;
}

extern "C" void kernel_launch(void* const* d_in, const int* in_sizes, int n_in,
                              void* d_out, int out_size, void* d_ws, size_t ws_size,
                              hipStream_t stream) {
    const float* x = (const float*)d_in[0];
    const int* batch = (const int*)d_in[1];
    const float* W1 = (const float*)d_in[3];
    const float* W2 = (const float*)d_in[4];
    const float* bias = (const float*)d_in[5];

    const int n = in_sizes[1];           // 500000 nodes
    const int b_gr = out_size / 256;     // 8192 graphs
    const int nchunks = (n + 63) >> 6;   // 7813
    const int span = (nchunks + GEMM_GRID - 1) / GEMM_GRID;

    char* ws = (char*)d_ws;
    unsigned short* w1p = (unsigned short*)ws;               // 160 KB
    int* seg = (int*)(ws + 163840);                          // (B+1)*4
    float* z = (float*)(ws + 262144);                        // B*320*4 = 10.5 MB
    unsigned short* h = (unsigned short*)(ws + 262144 +
                         (size_t)b_gr * NCH * sizeof(float)); // npad*320*2 = 320 MB

    seg_start_kernel<<<(b_gr + 256) / 256, 256, 0, stream>>>(batch, seg, n, b_gr);
    pack_w1_kernel<<<(NCG * 8 * 64 + 255) / 256, 256, 0, stream>>>(W1, w1p);
    gemm_h_kernel<<<GEMM_GRID, 512, 0, stream>>>(x, w1p, h, n, nchunks, span);
    reduce_kernel<<<b_gr, 320, 0, stream>>>(h, seg, z);
    k2_kernel<<<b_gr / 16, 256, 0, stream>>>(z, W2, bias, (float*)d_out);
}